// Round 12
// baseline (101.056 us; speedup 1.0000x reference)
//
#include <hip/hip_runtime.h>
#include <hip/hip_bf16.h>
#include <hip/hip_fp16.h>
#include <stdint.h>

// Problem constants
#define BATCH 256
#define NPOS 49
#define CCH 128
#define KWIN 7
#define HEADS 4
#define K2 49
#define HD 32
#define MROWS (BATCH * NPOS)         // 12544
#define QSCALE 0.17677669529663687f  // 32^-0.5

using short8 = __attribute__((ext_vector_type(8))) short;
using floatx4 = __attribute__((ext_vector_type(4))) float;

static __device__ inline short f2bf(float x) {
  uint32_t u = __float_as_uint(x);
  uint32_t r = (u + 0x7fffu + ((u >> 16) & 1u)) >> 16;
  return (short)r;
}

// ---------------------------------------------------------------------------
// Prep: pack [w_qkv; w_off] (776 x 128 f32) -> bf16 w_bf (row-major).
// ---------------------------------------------------------------------------
__global__ __launch_bounds__(256) void prep_wbf(const float* __restrict__ w_qkv,
                                                const float* __restrict__ w_off,
                                                short* __restrict__ w_bf) {
  int i = blockIdx.x * 256 + threadIdx.x;  // 8-elem chunks; 99328/8 = 12416
  if (i < 12416) {
    int e = i * 8;
    int row = e >> 7;
    int k = e & 127;
    const float* src =
        (row < 384) ? &w_qkv[row * 128 + k] : &w_off[(row - 384) * 128 + k];
    float4 f0 = *(const float4*)(src);
    float4 f1 = *(const float4*)(src + 4);
    short8 pk;
    pk[0] = f2bf(f0.x); pk[1] = f2bf(f0.y); pk[2] = f2bf(f0.z); pk[3] = f2bf(f0.w);
    pk[4] = f2bf(f1.x); pk[5] = f2bf(f1.y); pk[6] = f2bf(f1.z); pk[7] = f2bf(f1.w);
    *(short8*)&w_bf[e] = pk;
  }
}

// ---------------------------------------------------------------------------
// FUSED qkv/off projection + deformable window attention.
// One block per (b,h), 512 threads = 8 waves, 5 barriers.
//  P0 stage: x_b (49x128) -> bf16 xbs[64][136] (rows>=49 zero); zero A2f;
//     prefetch rpb bias to regs.
//  P1 GEMM (52 jobs, wave-strided): per head slice of x @ [w_qkv;w_off]^T.
//     Q/K: swapped operands (A=w,B=x) -> C[c][n]: lane = 4 consecutive c at
//       fixed n -> b64 writes into qbs/kbs[n][c] (bf16, pitch 40). +bias,
//       q scaled.
//     V: normal (A=x,B=w) -> C[n][d]: 4 consecutive n at fixed d -> b64
//       into vbT[d][n] (bf16, pitch 72). +bias.
//     OFF: swapped -> fp16 offlds[n][oc] (pitch 104) b64 writes. +bias.
//  P2 S0 = k@q^T via MFMA(A=k,B=q) -> b128 writes S0[n][m] (aliases xbs).
//  P3 scores: bilinear gather {base,+1,+7,+8} (clamped neighbors have
//     exactly-zero weights; finite garbage cols annihilated); exp (no
//     max-sub); scatter pe*w via 4 LDS atomics.
//  P4 A2f -> A2b bf16 [64][72] (aliases qbs/kbs), cols 48+ masked.
//  P5 AV + rowsum via MFMA (ones-B-frag); write UNNORMALIZED out + rs_buf;
//     normalization folded into proj GEMM.
// LDS 51.5 KB -> 3 blocks/CU.
// ---------------------------------------------------------------------------
__global__ __launch_bounds__(512, 6) void dwa_fused(
    const float* __restrict__ x, const short* __restrict__ w_bf,
    const float* __restrict__ b_qkv, const float* __restrict__ b_off,
    const float* __restrict__ rpb, float* __restrict__ attn_out,
    float* __restrict__ rs_buf) {
  __shared__ __align__(16) short xbs[64 * 136];   // 17408B; later S0 f32[2564]
  __shared__ __align__(16) short uQK[64 * 40 * 2];  // qbs+kbs; later A2b
  __shared__ __align__(16) short vbT[32 * 72];    // bf16 v^T [d][n]
  __shared__ __align__(16) __half offlds[49 * 104];
  __shared__ __align__(16) float A2f[2564];

  short* qbs = uQK;             // [64][40]
  short* kbs = uQK + 64 * 40;   // [64][40]
  short* A2b = uQK;             // [64][72] bf16 (aliases qbs/kbs after P2)
  float* S0 = (float*)xbs;      // [49*52]+tail (aliases xbs after P1)

  const int bid = blockIdx.x;
  const int swz = (bid & 7) * 128 + (bid >> 3);  // XCD swizzle
  const int b = swz >> 2;
  const int h = swz & 3;
  const int tid = threadIdx.x;
  const int lane = tid & 63;
  const int wv = tid >> 6;
  const int lr = lane & 15;
  const int lg = lane >> 4;

  // ---- prefetch rpb bias for my 5 score-slots ----
  float biasr[5];
#pragma unroll
  for (int p = 0; p < 5; ++p) {
    if (p < 4 || tid < 353) {  // 2401 = 4*512 + 353
      int e = tid + p * 512;
      unsigned nu = (unsigned)e / 49u;
      int k2 = e - (int)nu * 49;
      unsigned ku = (unsigned)k2;
      int ky = (int)(ku / 7u), kx = k2 - ky * 7;
      biasr[p] = rpb[h * 169 + (ky + 3) * 13 + (kx + 3)];
    }
  }

  // ---- P0: stage x -> bf16 xbs; zero pad rows; zero A2f ----
  {
    const float* xb = x + (size_t)(b * 49) * 128;
    for (int u = tid; u < 784; u += 512) {  // 49 rows x 16 chunks of 8
      int r = u >> 4;
      int c8 = (u & 15) * 8;
      const float* src = xb + r * 128 + c8;
      float4 f0 = *(const float4*)(src);
      float4 f1 = *(const float4*)(src + 4);
      short8 pk;
      pk[0] = f2bf(f0.x); pk[1] = f2bf(f0.y); pk[2] = f2bf(f0.z); pk[3] = f2bf(f0.w);
      pk[4] = f2bf(f1.x); pk[5] = f2bf(f1.y); pk[6] = f2bf(f1.z); pk[7] = f2bf(f1.w);
      *(short8*)&xbs[r * 136 + c8] = pk;
    }
    short8 zz = {0, 0, 0, 0, 0, 0, 0, 0};
    for (int u = tid; u < 255; u += 512) {  // rows 49..63 x 17 chunks
      int r = 49 + u / 17;
      int c8 = (u - (u / 17) * 17) * 8;
      *(short8*)&xbs[r * 136 + c8] = zz;
    }
    float4 z4 = make_float4(0.f, 0.f, 0.f, 0.f);
    for (int i = tid; i < 641; i += 512) ((float4*)A2f)[i] = z4;
  }
  __syncthreads();  // B0

  // ---- P1: fused projection GEMM (52 jobs) ----
  for (int j = wv; j < 52; j += 8) {
    const int ntile = j & 3;
    const int jj = j >> 2;  // 0,1=Q  2,3=K  4,5=V  6..12=OFF
    floatx4 acc = {0.f, 0.f, 0.f, 0.f};
    if (jj == 4 || jj == 5) {
      // ---- V: A=x (rows n by lr), B=w_v (cols d by lr) -> C[n][d] ----
      const int vc = (jj & 1) * 16;
      const short* xp = &xbs[(ntile * 16 + lr) * 136];
      const short* wp = w_bf + (size_t)(256 + h * 32 + vc + lr) * 128;
#pragma unroll
      for (int ks = 0; ks < 4; ++ks) {
        short8 af = *(const short8*)(xp + ks * 32 + lg * 8);
        short8 bf = *(const short8*)(wp + ks * 32 + lg * 8);
        acc = __builtin_amdgcn_mfma_f32_16x16x32_bf16(af, bf, acc, 0, 0, 0);
      }
      const int d = vc + lr;
      const float bv = b_qkv[256 + h * 32 + d];
      short4 pk;
      pk.x = f2bf(acc[0] + bv);
      pk.y = f2bf(acc[1] + bv);
      pk.z = f2bf(acc[2] + bv);
      pk.w = f2bf(acc[3] + bv);
      *(short4*)&vbT[d * 72 + ntile * 16 + lg * 4] = pk;
    } else {
      // ---- Q/K/OFF: A=w (rows c by lr), B=x (cols n by lr) -> C[c][n] ----
      int wrow;
      if (jj < 2) wrow = h * 32 + (jj & 1) * 16 + lr;
      else if (jj < 4) wrow = 128 + h * 32 + (jj & 1) * 16 + lr;
      else wrow = 384 + h * 98 + (jj - 6) * 16 + lr;
      const short* wp = w_bf + (size_t)wrow * 128;
      const short* xp = &xbs[(ntile * 16 + lr) * 136];
#pragma unroll
      for (int ks = 0; ks < 4; ++ks) {
        short8 af = *(const short8*)(wp + ks * 32 + lg * 8);
        short8 bf = *(const short8*)(xp + ks * 32 + lg * 8);
        acc = __builtin_amdgcn_mfma_f32_16x16x32_bf16(af, bf, acc, 0, 0, 0);
      }
      const int n = ntile * 16 + lr;
      if (jj < 2) {  // Q -> qbs, scaled
        const int c0 = (jj & 1) * 16 + lg * 4;
        float4 bb = *(const float4*)&b_qkv[h * 32 + c0];
        short4 pk;
        pk.x = f2bf((acc[0] + bb.x) * QSCALE);
        pk.y = f2bf((acc[1] + bb.y) * QSCALE);
        pk.z = f2bf((acc[2] + bb.z) * QSCALE);
        pk.w = f2bf((acc[3] + bb.w) * QSCALE);
        *(short4*)&qbs[n * 40 + c0] = pk;
      } else if (jj < 4) {  // K -> kbs
        const int c0 = (jj & 1) * 16 + lg * 4;
        float4 bb = *(const float4*)&b_qkv[128 + h * 32 + c0];
        short4 pk;
        pk.x = f2bf(acc[0] + bb.x);
        pk.y = f2bf(acc[1] + bb.y);
        pk.z = f2bf(acc[2] + bb.z);
        pk.w = f2bf(acc[3] + bb.w);
        *(short4*)&kbs[n * 40 + c0] = pk;
      } else {  // OFF -> offlds fp16
        const int oc0 = (jj - 6) * 16 + lg * 4;
        if (oc0 <= 96 && n < 49) {
          float v0 = acc[0] + b_off[h * 98 + oc0 + 0];
          float v1 = acc[1] + b_off[h * 98 + oc0 + 1];
          float v2 = acc[2] + b_off[h * 98 + oc0 + 2];
          float v3 = acc[3] + b_off[h * 98 + oc0 + 3];
          short4 pk;
          pk.x = (short)__half_as_ushort(__float2half(v0));
          pk.y = (short)__half_as_ushort(__float2half(v1));
          pk.z = (short)__half_as_ushort(__float2half(v2));
          pk.w = (short)__half_as_ushort(__float2half(v3));
          *(short4*)&offlds[n * 104 + oc0] = pk;
        }
      }
    }
  }
  __syncthreads();  // B1 (xbs dead -> S0 region)

  // ---- P2: S0[n][m] = k_m . q_n via mfma(A=k,B=q), wide b128 writes ----
  {
    const int nt = wv >> 1;
    const int mt2 = (wv & 1) * 2;
    const int n = nt * 16 + lr;
    short8 bf = *(const short8*)&qbs[n * 40 + lg * 8];
    floatx4 z = {0.f, 0.f, 0.f, 0.f};
#pragma unroll
    for (int t = 0; t < 2; ++t) {
      const int mt = mt2 + t;
      short8 af = *(const short8*)&kbs[(mt * 16 + lr) * 40 + lg * 8];
      floatx4 c = __builtin_amdgcn_mfma_f32_16x16x32_bf16(af, bf, z, 0, 0, 0);
      int mbase = mt * 16 + lg * 4;
      if (mbase < 52 && n < 49) {
        *(float4*)&S0[n * 52 + mbase] = make_float4(c[0], c[1], c[2], c[3]);
      }
    }
    if (tid < 16) S0[2548 + tid] = 0.f;  // zero tail
  }
  __syncthreads();  // B2

  // ---- P3: scores + exp + unnormalized scatter ----
#pragma unroll
  for (int p = 0; p < 5; ++p) {
    if (p < 4 || tid < 353) {
      int e = tid + p * 512;
      unsigned nu = (unsigned)e / 49u;
      int n = (int)nu;
      int k2 = e - n * 49;
      int iy = (int)(nu / 7u), ix = n - iy * 7;
      unsigned ku = (unsigned)k2;
      int ky = (int)(ku / 7u), kx = k2 - ky * 7;
      __half2 o2 = *(const __half2*)&offlds[n * 104 + k2 * 2];
      float2 off2 = __half22float2(o2);
      float py = fminf(fmaxf((float)(iy + ky - 3) + off2.x, 0.f), 6.f);
      float px = fminf(fmaxf((float)(ix + kx - 3) + off2.y, 0.f), 6.f);
      float y0f = floorf(py), x0f = floorf(px);
      float wy = py - y0f, wx = px - x0f;
      int base = n * 52 + (int)y0f * 7 + (int)x0f;
      float s00 = S0[base], s01 = S0[base + 1];
      float s10 = S0[base + 7], s11 = S0[base + 8];
      float w00 = (1.f - wy) * (1.f - wx);
      float w01 = (1.f - wy) * wx;
      float w10 = wy * (1.f - wx);
      float w11 = wy * wx;
      float s = w00 * s00 + w01 * s01 + w10 * s10 + w11 * s11 + biasr[p];
      float pe = __expf(s);  // |s| small: exp-safe without max-sub
      atomicAdd(&A2f[base], pe * w00);
      atomicAdd(&A2f[base + 1], pe * w01);
      atomicAdd(&A2f[base + 7], pe * w10);
      atomicAdd(&A2f[base + 8], pe * w11);
    }
  }
  __syncthreads();  // B3

  // ---- P4: A2f -> A2b bf16 [64][72], cols 48..63 masked {A2[48],0,...} ----
  if (tid < 392) {
    int n = tid >> 3;
    int j8 = tid & 7;
    short8 pk = {0, 0, 0, 0, 0, 0, 0, 0};
    if (j8 < 6) {
      const float* src = &A2f[n * 52 + j8 * 8];
      float4 f0 = *(const float4*)(src);
      float4 f1 = *(const float4*)(src + 4);
      pk[0] = f2bf(f0.x); pk[1] = f2bf(f0.y); pk[2] = f2bf(f0.z); pk[3] = f2bf(f0.w);
      pk[4] = f2bf(f1.x); pk[5] = f2bf(f1.y); pk[6] = f2bf(f1.z); pk[7] = f2bf(f1.w);
    } else if (j8 == 6) {
      float4 f0 = *(const float4*)&A2f[n * 52 + 48];
      pk[0] = f2bf(f0.x);  // col 48 only; 49..51 forced zero
    }
    *(short8*)&A2b[n * 72 + j8 * 8] = pk;
  }
  __syncthreads();  // B4

  // ---- P5: out[n][d] = A2b[n].vbT[d] (unnormalized) + rowsum MFMA ----
  {
    const int nt = wv >> 1;
    const int dt = wv & 1;
    floatx4 acc = {0.f, 0.f, 0.f, 0.f};
    floatx4 accS = {0.f, 0.f, 0.f, 0.f};
    short8 bones;
#pragma unroll
    for (int u = 0; u < 8; ++u) bones[u] = (lr == 0) ? (short)0x3F80 : (short)0;
#pragma unroll
    for (int ks = 0; ks < 2; ++ks) {
      short8 af = *(const short8*)&A2b[(nt * 16 + lr) * 72 + ks * 32 + lg * 8];
      short8 bf = *(const short8*)&vbT[(dt * 16 + lr) * 72 + ks * 32 + lg * 8];
      acc = __builtin_amdgcn_mfma_f32_16x16x32_bf16(af, bf, acc, 0, 0, 0);
      if (dt == 0)
        accS = __builtin_amdgcn_mfma_f32_16x16x32_bf16(af, bones, accS, 0, 0, 0);
    }
    const int d = dt * 16 + lr;
#pragma unroll
    for (int reg = 0; reg < 4; ++reg) {
      int n = nt * 16 + lg * 4 + reg;
      if (n < 49) {
        attn_out[(size_t)(b * 49 + n) * 128 + h * 32 + d] = acc[reg];
        if (dt == 0 && lr == 0)
          rs_buf[(size_t)(b * 49 + n) * 4 + h] = accS[reg];
      }
    }
  }
}

// ---------------------------------------------------------------------------
// Proj GEMM (r11's MODE 1): out = diag(1/rs per head) * attn_out @ w_proj^T
// ---------------------------------------------------------------------------
__global__ __launch_bounds__(256) void dwa_proj(
    const float* __restrict__ A, const float* __restrict__ W0,
    const float* __restrict__ bias0, float* __restrict__ out0,
    const float* __restrict__ rs) {
  __shared__ short Abs[64][128];
  __shared__ short Bbs[64][128];
  const int tid = threadIdx.x;
  const int m0 = blockIdx.x * 64;
  const int n0 = blockIdx.y * 64;

#pragma unroll
  for (int p = 0; p < 4; ++p) {
    int c = tid + p * 256;
    int row = c >> 4;
    int slot = c & 15;
    const float* src = A + (size_t)(m0 + row) * 128 + slot * 8;
    float4 f0 = *(const float4*)(src);
    float4 f1 = *(const float4*)(src + 4);
    float irs = 1.0f / rs[(size_t)(m0 + row) * 4 + (slot >> 2)];
    f0.x *= irs; f0.y *= irs; f0.z *= irs; f0.w *= irs;
    f1.x *= irs; f1.y *= irs; f1.z *= irs; f1.w *= irs;
    short8 pk;
    pk[0] = f2bf(f0.x); pk[1] = f2bf(f0.y); pk[2] = f2bf(f0.z); pk[3] = f2bf(f0.w);
    pk[4] = f2bf(f1.x); pk[5] = f2bf(f1.y); pk[6] = f2bf(f1.z); pk[7] = f2bf(f1.w);
    *(short8*)&Abs[row][(slot ^ (row & 7)) * 8] = pk;
  }
#pragma unroll
  for (int p = 0; p < 4; ++p) {
    int c = tid + p * 256;
    int row = c >> 4;
    int slot = c & 15;
    const float* src = W0 + (size_t)(n0 + row) * 128 + slot * 8;
    float4 f0 = *(const float4*)(src);
    float4 f1 = *(const float4*)(src + 4);
    short8 pk;
    pk[0] = f2bf(f0.x); pk[1] = f2bf(f0.y); pk[2] = f2bf(f0.z); pk[3] = f2bf(f0.w);
    pk[4] = f2bf(f1.x); pk[5] = f2bf(f1.y); pk[6] = f2bf(f1.z); pk[7] = f2bf(f1.w);
    *(short8*)&Bbs[row][(slot ^ (row & 7)) * 8] = pk;
  }
  __syncthreads();

  const int lane = tid & 63;
  const int wv = tid >> 6;
  const int wrow = (wv >> 1) * 32;
  const int wcol = (wv & 1) * 32;
  const int lr = lane & 15;
  const int lg = lane >> 4;

  floatx4 acc[2][2];
#pragma unroll
  for (int i = 0; i < 2; ++i)
#pragma unroll
    for (int j = 0; j < 2; ++j) acc[i][j] = {0.f, 0.f, 0.f, 0.f};

#pragma unroll
  for (int ks = 0; ks < 4; ++ks) {
    short8 af[2], bf[2];
#pragma unroll
    for (int i = 0; i < 2; ++i) {
      int r = wrow + i * 16 + lr;
      int slot = (ks * 4 + lg) ^ (r & 7);
      af[i] = *(const short8*)&Abs[r][slot * 8];
    }
#pragma unroll
    for (int j = 0; j < 2; ++j) {
      int r = wcol + j * 16 + lr;
      int slot = (ks * 4 + lg) ^ (r & 7);
      bf[j] = *(const short8*)&Bbs[r][slot * 8];
    }
#pragma unroll
    for (int i = 0; i < 2; ++i)
#pragma unroll
      for (int j = 0; j < 2; ++j)
        acc[i][j] = __builtin_amdgcn_mfma_f32_16x16x32_bf16(af[i], bf[j],
                                                            acc[i][j], 0, 0, 0);
  }

#pragma unroll
  for (int i = 0; i < 2; ++i) {
#pragma unroll
    for (int reg = 0; reg < 4; ++reg) {
      int grow = m0 + wrow + i * 16 + lg * 4 + reg;
#pragma unroll
      for (int j = 0; j < 2; ++j) {
        int gcol = n0 + wcol + j * 16 + lr;
        out0[(size_t)grow * 128 + gcol] = acc[i][j][reg] + bias0[gcol];
      }
    }
  }
}

// ---------------------------------------------------------------------------
extern "C" void kernel_launch(void* const* d_in, const int* in_sizes, int n_in,
                              void* d_out, int out_size, void* d_ws,
                              size_t ws_size, hipStream_t stream) {
  const float* x = (const float*)d_in[0];
  const float* w_qkv = (const float*)d_in[1];
  const float* b_qkv = (const float*)d_in[2];
  const float* w_off = (const float*)d_in[3];
  const float* b_off = (const float*)d_in[4];
  const float* rpb = (const float*)d_in[5];
  const float* w_proj = (const float*)d_in[6];
  const float* b_proj = (const float*)d_in[7];
  float* out = (float*)d_out;

  short* w_bf = (short*)d_ws;                          // 776*128 bf16 = 198656B
  float* attn_out = (float*)((char*)d_ws + 198656);    // 12544*128 f32
  float* rs_buf = attn_out + (size_t)MROWS * 128;      // 12544*4 f32

  prep_wbf<<<49, 256, 0, stream>>>(w_qkv, w_off, w_bf);
  dwa_fused<<<BATCH * HEADS, 512, 0, stream>>>(x, w_bf, b_qkv, b_off, rpb,
                                               attn_out, rs_buf);
  dwa_proj<<<dim3(196, 2), 256, 0, stream>>>(attn_out, w_proj, b_proj, out,
                                             rs_buf);
}

// Round 14
// 96.611 us; speedup vs baseline: 1.0460x; 1.0460x over previous
//
#include <hip/hip_runtime.h>
#include <hip/hip_bf16.h>
#include <hip/hip_fp16.h>
#include <stdint.h>

// Problem constants
#define BATCH 256
#define NPOS 49
#define CCH 128
#define KWIN 7
#define HEADS 4
#define K2 49
#define HD 32
#define MROWS (BATCH * NPOS)         // 12544
#define QSCALE 0.17677669529663687f  // 32^-0.5

using short8 = __attribute__((ext_vector_type(8))) short;
using floatx4 = __attribute__((ext_vector_type(4))) float;

static __device__ inline short f2bf(float x) {
  uint32_t u = __float_as_uint(x);
  uint32_t r = (u + 0x7fffu + ((u >> 16) & 1u)) >> 16;
  return (short)r;
}

// ---------------------------------------------------------------------------
// bf16 MFMA GEMM (r11): C[M x N] = A[M x 128] @ W^T + bias
// MODE 1 scales A rows per 32-col head-group by 1/rs[row][head].
// ---------------------------------------------------------------------------
template <int MODE>
__global__ __launch_bounds__(256) void dwa_gemm(
    const float* __restrict__ A, const float* __restrict__ W0,
    const float* __restrict__ W1, const float* __restrict__ bias0,
    const float* __restrict__ bias1, float* __restrict__ out0,
    float* __restrict__ out1, const float* __restrict__ rs) {
  __shared__ short Abs[64][128];
  __shared__ short Bbs[64][128];
  const int tid = threadIdx.x;
  const int m0 = blockIdx.x * 64;
  const int n0 = blockIdx.y * 64;

#pragma unroll
  for (int p = 0; p < 4; ++p) {
    int c = tid + p * 256;
    int row = c >> 4;
    int slot = c & 15;
    const float* src = A + (size_t)(m0 + row) * 128 + slot * 8;
    float4 f0 = *(const float4*)(src);
    float4 f1 = *(const float4*)(src + 4);
    if (MODE == 1) {
      float irs = 1.0f / rs[(size_t)(m0 + row) * 4 + (slot >> 2)];
      f0.x *= irs; f0.y *= irs; f0.z *= irs; f0.w *= irs;
      f1.x *= irs; f1.y *= irs; f1.z *= irs; f1.w *= irs;
    }
    short8 pk;
    pk[0] = f2bf(f0.x); pk[1] = f2bf(f0.y); pk[2] = f2bf(f0.z); pk[3] = f2bf(f0.w);
    pk[4] = f2bf(f1.x); pk[5] = f2bf(f1.y); pk[6] = f2bf(f1.z); pk[7] = f2bf(f1.w);
    *(short8*)&Abs[row][(slot ^ (row & 7)) * 8] = pk;
  }
#pragma unroll
  for (int p = 0; p < 4; ++p) {
    int c = tid + p * 256;
    int row = c >> 4;
    int slot = c & 15;
    int colg = n0 + row;
    float4 f0 = make_float4(0.f, 0.f, 0.f, 0.f), f1 = f0;
    if (MODE == 1 || colg < 384) {
      const float* src = W0 + (size_t)colg * 128 + slot * 8;
      f0 = *(const float4*)(src);
      f1 = *(const float4*)(src + 4);
    } else if (colg < 776) {
      const float* src = W1 + (size_t)(colg - 384) * 128 + slot * 8;
      f0 = *(const float4*)(src);
      f1 = *(const float4*)(src + 4);
    }
    short8 pk;
    pk[0] = f2bf(f0.x); pk[1] = f2bf(f0.y); pk[2] = f2bf(f0.z); pk[3] = f2bf(f0.w);
    pk[4] = f2bf(f1.x); pk[5] = f2bf(f1.y); pk[6] = f2bf(f1.z); pk[7] = f2bf(f1.w);
    *(short8*)&Bbs[row][(slot ^ (row & 7)) * 8] = pk;
  }
  __syncthreads();

  const int lane = tid & 63;
  const int wv = tid >> 6;
  const int wrow = (wv >> 1) * 32;
  const int wcol = (wv & 1) * 32;
  const int lr = lane & 15;
  const int lg = lane >> 4;

  floatx4 acc[2][2];
#pragma unroll
  for (int i = 0; i < 2; ++i)
#pragma unroll
    for (int j = 0; j < 2; ++j) acc[i][j] = {0.f, 0.f, 0.f, 0.f};

#pragma unroll
  for (int ks = 0; ks < 4; ++ks) {
    short8 af[2], bf[2];
#pragma unroll
    for (int i = 0; i < 2; ++i) {
      int r = wrow + i * 16 + lr;
      int slot = (ks * 4 + lg) ^ (r & 7);
      af[i] = *(const short8*)&Abs[r][slot * 8];
    }
#pragma unroll
    for (int j = 0; j < 2; ++j) {
      int r = wcol + j * 16 + lr;
      int slot = (ks * 4 + lg) ^ (r & 7);
      bf[j] = *(const short8*)&Bbs[r][slot * 8];
    }
#pragma unroll
    for (int i = 0; i < 2; ++i)
#pragma unroll
      for (int j = 0; j < 2; ++j)
        acc[i][j] = __builtin_amdgcn_mfma_f32_16x16x32_bf16(af[i], bf[j],
                                                            acc[i][j], 0, 0, 0);
  }

#pragma unroll
  for (int i = 0; i < 2; ++i) {
#pragma unroll
    for (int reg = 0; reg < 4; ++reg) {
      int grow = m0 + wrow + i * 16 + lg * 4 + reg;
#pragma unroll
      for (int j = 0; j < 2; ++j) {
        int gcol = n0 + wcol + j * 16 + lr;
        float v = acc[i][j][reg];
        if (MODE == 1) {
          out0[(size_t)grow * 128 + gcol] = v + bias0[gcol];
        } else {
          if (gcol < 384) {
            float sc = (gcol < 128) ? QSCALE : 1.0f;
            out0[(size_t)grow * 384 + gcol] = (v + bias0[gcol]) * sc;
          } else if (gcol < 776) {
            out1[(size_t)grow * 392 + (gcol - 384)] = v + bias1[gcol - 384];
          }
        }
      }
    }
  }
}

// ---------------------------------------------------------------------------
// Deformable window attention, split-rows: one block per (b, h, half).
// 2048 blocks x 256 threads (4 waves); LDS 20416 B -> 8 blocks/CU -> ALL
// blocks co-resident (one scheduling round, max cross-block desync).
// half 0: local rows 0..24 (25); half 1: rows 25..48 (24). k/v staged fully.
// r13 bug fixed: P2 write guard must include mbase < 52 (S0h row pitch) --
// without it, mt==3/lg>=1 short4 writes spill ZEROS (kbs rows 52+ are
// zero-padded) into row n+1 cols 0..11, racing/corrupting real scores.
// ---------------------------------------------------------------------------
__global__ __launch_bounds__(256, 8) void dwa_attn(
    const float* __restrict__ qkv_buf, const float* __restrict__ off_buf,
    const float* __restrict__ rpb, float* __restrict__ attn_out,
    float* __restrict__ rs_buf) {
  __shared__ __align__(16) short region1[3840];  // qbs(1280)+kbs(2560) / A2b
  __shared__ __align__(16) __half S0h[1356];     // [26][52] fp16 + pad
  __shared__ __align__(16) short vbT[32 * 72];   // bf16 v^T [d][m]
  __shared__ __align__(16) float A2f[1354];      // [26][52] f32 + pad

  short* qbs = region1;          // [32][40] bf16
  short* kbs = region1 + 1280;   // [64][40] bf16
  short* A2b = region1;          // [32][72] bf16 (aliases qbs/kbs after P2)

  // 2048 blocks: XCD swizzle keeps the 8 sub-problems of one b together.
  const int bid = blockIdx.x;
  const int swz = (bid & 7) * 256 + (bid >> 3);
  const int b = swz >> 3;
  const int sub = swz & 7;
  const int h = sub >> 1;
  const int half = sub & 1;
  const int bn0 = half * 25;            // first local row
  const int rcnt = half ? 24 : 25;      // rows this block owns
  const int nslots = rcnt * 49;         // 1225 / 1176

  const int tid = threadIdx.x;
  const int lane = tid & 63;
  const int wv = tid >> 6;
  const int lr = lane & 15;
  const int lg = lane >> 4;

  // ---- prefetch offsets + bias to regs (consumed in P3) ----
  const float* offp = off_buf + (size_t)(b * 49) * 392 + h * 98;
  float2 offr[5];
  float biasr[5];
#pragma unroll
  for (int p = 0; p < 5; ++p) {
    int e = tid + p * 256;
    if (e < nslots) {
      unsigned nu = (unsigned)e / 49u;
      int k2 = e - (int)nu * 49;
      unsigned ku = (unsigned)k2;
      int ky = (int)(ku / 7u), kx = k2 - ky * 7;
      offr[p] = *(const float2*)(offp + (size_t)(bn0 + (int)nu) * 392 + k2 * 2);
      biasr[p] = rpb[h * 169 + (ky + 3) * 13 + (kx + 3)];
    }
  }

  // ---- P1 stage ----
  {
    short8 zz = {0, 0, 0, 0, 0, 0, 0, 0};
    // k rows 0..63 (>=49 zero)
    {
      int r = tid >> 2, c4 = tid & 3;
      short8 pk = zz;
      if (r < 49) {
        const float* src =
            qkv_buf + (size_t)(b * 49 + r) * 384 + 128 + h * 32 + c4 * 8;
        float4 f0 = *(const float4*)(src);
        float4 f1 = *(const float4*)(src + 4);
        pk[0] = f2bf(f0.x); pk[1] = f2bf(f0.y); pk[2] = f2bf(f0.z); pk[3] = f2bf(f0.w);
        pk[4] = f2bf(f1.x); pk[5] = f2bf(f1.y); pk[6] = f2bf(f1.z); pk[7] = f2bf(f1.w);
      }
      *(short8*)&kbs[r * 40 + c4 * 8] = pk;
    }
    // q own rows 0..31 (>=rcnt zero)
    if (tid < 128) {
      int r = tid >> 2, c4 = tid & 3;
      short8 pk = zz;
      if (r < rcnt) {
        const float* src =
            qkv_buf + (size_t)(b * 49 + bn0 + r) * 384 + h * 32 + c4 * 8;
        float4 f0 = *(const float4*)(src);
        float4 f1 = *(const float4*)(src + 4);
        pk[0] = f2bf(f0.x); pk[1] = f2bf(f0.y); pk[2] = f2bf(f0.z); pk[3] = f2bf(f0.w);
        pk[4] = f2bf(f1.x); pk[5] = f2bf(f1.y); pk[6] = f2bf(f1.z); pk[7] = f2bf(f1.w);
      }
      *(short8*)&qbs[r * 40 + c4 * 8] = pk;
    }
    // v transposed (full 49 rows)
    const float* vbase = qkv_buf + (size_t)(b * 49) * 384 + 256 + h * 32;
#pragma unroll
    for (int it = 0; it < 7; ++it) {
      int i = tid + it * 256;
      if (i < 1568) {
        int n = i >> 5;
        int d = i & 31;
        vbT[d * 72 + n] = f2bf(vbase[(size_t)n * 384 + d]);
      }
    }
    for (int i = tid; i < 480; i += 256) {  // zero vbT cols 49..63, all d
      int d = i / 15;
      int j = i - d * 15;
      vbT[d * 72 + 49 + j] = 0;
    }
    // zero A2f ([26][52] = 1352 floats; 338 float4 + tail scalars)
    float4 z4 = make_float4(0.f, 0.f, 0.f, 0.f);
    for (int i = tid; i < 338; i += 256) *(float4*)&A2f[i * 4] = z4;
    if (tid < 2) A2f[1352 + tid] = 0.f;
    // zero S0h row-25 head (gather from row 24 reads into it)
    if (tid < 16) S0h[25 * 52 + tid] = __float2half(0.f);
  }
  __syncthreads();  // B1

  // ---- P2: S0h[n][m] = k_m . q_n via mfma(A=k, B=q); fp16 b64 writes ----
  {
    const int mt = wv;  // m-tile 0..3
    short8 af = *(const short8*)&kbs[(mt * 16 + lr) * 40 + lg * 8];
    floatx4 z = {0.f, 0.f, 0.f, 0.f};
#pragma unroll
    for (int nt = 0; nt < 2; ++nt) {
      short8 bf = *(const short8*)&qbs[(nt * 16 + lr) * 40 + lg * 8];
      floatx4 c = __builtin_amdgcn_mfma_f32_16x16x32_bf16(af, bf, z, 0, 0, 0);
      int n = nt * 16 + lr;            // C col = n
      int mbase = mt * 16 + lg * 4;    // C rows = m..m+3
      if (n < 26 && mbase < 52) {      // r13 FIX: mbase guard (row pitch 52)
        short4 pk;
        pk.x = (short)__half_as_ushort(__float2half(c[0]));
        pk.y = (short)__half_as_ushort(__float2half(c[1]));
        pk.z = (short)__half_as_ushort(__float2half(c[2]));
        pk.w = (short)__half_as_ushort(__float2half(c[3]));
        *(short4*)&S0h[n * 52 + mbase] = pk;
      }
    }
  }
  __syncthreads();  // B2 (q/k region dead for reads after this)

  // ---- P3: scores + exp + unnormalized scatter ----
#pragma unroll
  for (int p = 0; p < 5; ++p) {
    int e = tid + p * 256;
    if (e < nslots) {
      unsigned nu = (unsigned)e / 49u;
      int n = (int)nu;                 // local row
      int k2 = e - n * 49;
      int gn = bn0 + n;
      unsigned gnu = (unsigned)gn;
      int iy = (int)(gnu / 7u), ix = gn - iy * 7;
      unsigned ku = (unsigned)k2;
      int ky = (int)(ku / 7u), kx = k2 - ky * 7;
      float py = fminf(fmaxf((float)(iy + ky - 3) + offr[p].x, 0.f), 6.f);
      float px = fminf(fmaxf((float)(ix + kx - 3) + offr[p].y, 0.f), 6.f);
      float y0f = floorf(py), x0f = floorf(px);
      float wy = py - y0f, wx = px - x0f;
      int base = n * 52 + (int)y0f * 7 + (int)x0f;
      float s00 = __half2float(S0h[base]);
      float s01 = __half2float(S0h[base + 1]);
      float s10 = __half2float(S0h[base + 7]);
      float s11 = __half2float(S0h[base + 8]);
      float w00 = (1.f - wy) * (1.f - wx);
      float w01 = (1.f - wy) * wx;
      float w10 = wy * (1.f - wx);
      float w11 = wy * wx;
      float s = w00 * s00 + w01 * s01 + w10 * s10 + w11 * s11 + biasr[p];
      float pe = __expf(s);  // |s| small: exp-safe without max-sub
      atomicAdd(&A2f[base], pe * w00);
      atomicAdd(&A2f[base + 1], pe * w01);
      atomicAdd(&A2f[base + 7], pe * w10);
      atomicAdd(&A2f[base + 8], pe * w11);
    }
  }
  __syncthreads();  // B3

  // ---- P4: A2f -> A2b bf16 [32][72] (aliases q/k region); cols 48+ masked
  if (tid < 208) {  // 26 rows x 8 chunks
    int n = tid >> 3;
    int j8 = tid & 7;
    short8 pk = {0, 0, 0, 0, 0, 0, 0, 0};
    if (j8 < 6) {
      const float* src = &A2f[n * 52 + j8 * 8];
      float4 f0 = *(const float4*)(src);
      float4 f1 = *(const float4*)(src + 4);
      pk[0] = f2bf(f0.x); pk[1] = f2bf(f0.y); pk[2] = f2bf(f0.z); pk[3] = f2bf(f0.w);
      pk[4] = f2bf(f1.x); pk[5] = f2bf(f1.y); pk[6] = f2bf(f1.z); pk[7] = f2bf(f1.w);
    } else if (j8 == 6) {
      pk[0] = f2bf(A2f[n * 52 + 48]);  // col 48; 49..55 zero
    }  // j8==7: cols 56..63 zero
    *(short8*)&A2b[n * 72 + j8 * 8] = pk;
  }
  __syncthreads();  // B4

  // ---- P5: out[n][d] = A2b[n].vbT[d] (unnormalized) + rowsum MFMA ----
  {
    const int nt = wv & 1;   // n-tile 0..1
    const int dt = wv >> 1;  // d-tile 0..1
    floatx4 acc = {0.f, 0.f, 0.f, 0.f};
    floatx4 accS = {0.f, 0.f, 0.f, 0.f};
    short8 bones;
#pragma unroll
    for (int u = 0; u < 8; ++u) bones[u] = (lr == 0) ? (short)0x3F80 : (short)0;
#pragma unroll
    for (int ks = 0; ks < 2; ++ks) {
      short8 af = *(const short8*)&A2b[(nt * 16 + lr) * 72 + ks * 32 + lg * 8];
      short8 bf = *(const short8*)&vbT[(dt * 16 + lr) * 72 + ks * 32 + lg * 8];
      acc = __builtin_amdgcn_mfma_f32_16x16x32_bf16(af, bf, acc, 0, 0, 0);
      if (dt == 0)
        accS = __builtin_amdgcn_mfma_f32_16x16x32_bf16(af, bones, accS, 0, 0, 0);
    }
    const int d = dt * 16 + lr;
#pragma unroll
    for (int reg = 0; reg < 4; ++reg) {
      int n = nt * 16 + lg * 4 + reg;
      if (n < rcnt) {
        int grow = b * 49 + bn0 + n;
        attn_out[(size_t)grow * 128 + h * 32 + d] = acc[reg];
        if (dt == 0 && lr == 0) rs_buf[(size_t)grow * 4 + h] = accS[reg];
      }
    }
  }
}

// ---------------------------------------------------------------------------
extern "C" void kernel_launch(void* const* d_in, const int* in_sizes, int n_in,
                              void* d_out, int out_size, void* d_ws,
                              size_t ws_size, hipStream_t stream) {
  const float* x = (const float*)d_in[0];
  const float* w_qkv = (const float*)d_in[1];
  const float* b_qkv = (const float*)d_in[2];
  const float* w_off = (const float*)d_in[3];
  const float* b_off = (const float*)d_in[4];
  const float* rpb = (const float*)d_in[5];
  const float* w_proj = (const float*)d_in[6];
  const float* b_proj = (const float*)d_in[7];
  float* out = (float*)d_out;

  float* ws = (float*)d_ws;
  float* qkv_buf = ws;                              // 12544*384
  float* off_buf = qkv_buf + (size_t)MROWS * 384;   // 12544*392
  float* attn_out = off_buf + (size_t)MROWS * 392;  // 12544*128
  float* rs_buf = attn_out + (size_t)MROWS * 128;   // 12544*4

  dwa_gemm<0><<<dim3(196, 13), 256, 0, stream>>>(
      x, w_qkv, w_off, b_qkv, b_off, qkv_buf, off_buf, nullptr);
  dwa_attn<<<2048, 256, 0, stream>>>(qkv_buf, off_buf, rpb, attn_out, rs_buf);
  dwa_gemm<1><<<dim3(196, 2), 256, 0, stream>>>(
      attn_out, w_proj, nullptr, b_proj, nullptr, out, nullptr, rs_buf);
}

// Round 15
// 94.248 us; speedup vs baseline: 1.0722x; 1.0251x over previous
//
#include <hip/hip_runtime.h>
#include <hip/hip_bf16.h>
#include <hip/hip_fp16.h>
#include <stdint.h>

// Problem constants
#define BATCH 256
#define NPOS 49
#define CCH 128
#define KWIN 7
#define HEADS 4
#define K2 49
#define HD 32
#define MROWS (BATCH * NPOS)         // 12544
#define QSCALE 0.17677669529663687f  // 32^-0.5

using short8 = __attribute__((ext_vector_type(8))) short;
using floatx4 = __attribute__((ext_vector_type(4))) float;

static __device__ inline short f2bf(float x) {
  uint32_t u = __float_as_uint(x);
  uint32_t r = (u + 0x7fffu + ((u >> 16) & 1u)) >> 16;
  return (short)r;
}

// ---------------------------------------------------------------------------
// GEMM 0: x (12544x128 f32) @ [w_qkv;w_off]^T -> qkv_bf (bf16, q pre-scaled)
// + off_h (fp16). Grid (196, 5): each block stages its A-panel ONCE and
// loops N-tiles {y, y+5, y+10} (<13) -> x HBM re-reads 13x -> 5x.
// ---------------------------------------------------------------------------
__global__ __launch_bounds__(256) void dwa_gemm0(
    const float* __restrict__ x, const float* __restrict__ w_qkv,
    const float* __restrict__ w_off, const float* __restrict__ b_qkv,
    const float* __restrict__ b_off, short* __restrict__ qkv_bf,
    __half* __restrict__ off_h) {
  __shared__ short Abs[64][128];
  __shared__ short Bbs[64][128];
  const int tid = threadIdx.x;
  const int m0 = blockIdx.x * 64;

  // ---- stage A once (bf16, XOR-swizzled 16B slots) ----
#pragma unroll
  for (int p = 0; p < 4; ++p) {
    int c = tid + p * 256;
    int row = c >> 4;
    int slot = c & 15;
    const float* src = x + (size_t)(m0 + row) * 128 + slot * 8;
    float4 f0 = *(const float4*)(src);
    float4 f1 = *(const float4*)(src + 4);
    short8 pk;
    pk[0] = f2bf(f0.x); pk[1] = f2bf(f0.y); pk[2] = f2bf(f0.z); pk[3] = f2bf(f0.w);
    pk[4] = f2bf(f1.x); pk[5] = f2bf(f1.y); pk[6] = f2bf(f1.z); pk[7] = f2bf(f1.w);
    *(short8*)&Abs[row][(slot ^ (row & 7)) * 8] = pk;
  }

  const int lane = tid & 63;
  const int wv = tid >> 6;
  const int wrow = (wv >> 1) * 32;
  const int wcol = (wv & 1) * 32;
  const int lr = lane & 15;
  const int lg = lane >> 4;

#pragma unroll
  for (int t = 0; t < 3; ++t) {
    const int ntile = blockIdx.y + 5 * t;
    if (ntile >= 13) break;
    const int n0 = ntile * 64;
    // ---- stage B tile ----
#pragma unroll
    for (int p = 0; p < 4; ++p) {
      int c = tid + p * 256;
      int row = c >> 4;
      int slot = c & 15;
      int colg = n0 + row;
      float4 f0 = make_float4(0.f, 0.f, 0.f, 0.f), f1 = f0;
      if (colg < 384) {
        const float* src = w_qkv + (size_t)colg * 128 + slot * 8;
        f0 = *(const float4*)(src);
        f1 = *(const float4*)(src + 4);
      } else if (colg < 776) {
        const float* src = w_off + (size_t)(colg - 384) * 128 + slot * 8;
        f0 = *(const float4*)(src);
        f1 = *(const float4*)(src + 4);
      }
      short8 pk;
      pk[0] = f2bf(f0.x); pk[1] = f2bf(f0.y); pk[2] = f2bf(f0.z); pk[3] = f2bf(f0.w);
      pk[4] = f2bf(f1.x); pk[5] = f2bf(f1.y); pk[6] = f2bf(f1.z); pk[7] = f2bf(f1.w);
      *(short8*)&Bbs[row][(slot ^ (row & 7)) * 8] = pk;
    }
    __syncthreads();

    floatx4 acc[2][2];
#pragma unroll
    for (int i = 0; i < 2; ++i)
#pragma unroll
      for (int j = 0; j < 2; ++j) acc[i][j] = {0.f, 0.f, 0.f, 0.f};
#pragma unroll
    for (int ks = 0; ks < 4; ++ks) {
      short8 af[2], bf[2];
#pragma unroll
      for (int i = 0; i < 2; ++i) {
        int r = wrow + i * 16 + lr;
        int slot = (ks * 4 + lg) ^ (r & 7);
        af[i] = *(const short8*)&Abs[r][slot * 8];
      }
#pragma unroll
      for (int j = 0; j < 2; ++j) {
        int r = wcol + j * 16 + lr;
        int slot = (ks * 4 + lg) ^ (r & 7);
        bf[j] = *(const short8*)&Bbs[r][slot * 8];
      }
#pragma unroll
      for (int i = 0; i < 2; ++i)
#pragma unroll
        for (int j = 0; j < 2; ++j)
          acc[i][j] = __builtin_amdgcn_mfma_f32_16x16x32_bf16(af[i], bf[j],
                                                              acc[i][j], 0, 0, 0);
    }
    // ---- epilogue: bf16 qkv (q scaled) / fp16 off ----
#pragma unroll
    for (int i = 0; i < 2; ++i) {
#pragma unroll
      for (int reg = 0; reg < 4; ++reg) {
        int grow = m0 + wrow + i * 16 + lg * 4 + reg;
#pragma unroll
        for (int j = 0; j < 2; ++j) {
          int gcol = n0 + wcol + j * 16 + lr;
          float v = acc[i][j][reg];
          if (gcol < 384) {
            float sc = (gcol < 128) ? QSCALE : 1.0f;
            qkv_bf[(size_t)grow * 384 + gcol] = f2bf((v + b_qkv[gcol]) * sc);
          } else if (gcol < 776) {
            off_h[(size_t)grow * 392 + (gcol - 384)] =
                __float2half(v + b_off[gcol - 384]);
          }
        }
      }
    }
    __syncthreads();  // Bbs reads done before next stage
  }
}

// ---------------------------------------------------------------------------
// Deformable window attention, split-rows (r14 structure, bf16/fp16 inputs).
// One block per (b, h, half); 2048 blocks x 256 threads; LDS 20416 B.
// Staging is now pure short8 copies (producer already bf16) -> half the
// HBM fetch, ~100 fewer VALU/thread.
// ---------------------------------------------------------------------------
__global__ __launch_bounds__(256, 8) void dwa_attn(
    const short* __restrict__ qkv_bf, const __half* __restrict__ off_h,
    const float* __restrict__ rpb, float* __restrict__ attn_out,
    float* __restrict__ rs_buf) {
  __shared__ __align__(16) short region1[3840];  // qbs(1280)+kbs(2560) / A2b
  __shared__ __align__(16) __half S0h[1356];     // [26][52] fp16 + pad
  __shared__ __align__(16) short vbT[32 * 72];   // bf16 v^T [d][m]
  __shared__ __align__(16) float A2f[1354];      // [26][52] f32 + pad

  short* qbs = region1;          // [32][40] bf16
  short* kbs = region1 + 1280;   // [64][40] bf16
  short* A2b = region1;          // [32][72] bf16 (aliases qbs/kbs after P2)

  const int bid = blockIdx.x;
  const int swz = (bid & 7) * 256 + (bid >> 3);
  const int b = swz >> 3;
  const int sub = swz & 7;
  const int h = sub >> 1;
  const int half = sub & 1;
  const int bn0 = half * 25;
  const int rcnt = half ? 24 : 25;
  const int nslots = rcnt * 49;

  const int tid = threadIdx.x;
  const int lane = tid & 63;
  const int wv = tid >> 6;
  const int lr = lane & 15;
  const int lg = lane >> 4;

  // ---- prefetch offsets (fp16) + bias to regs ----
  const __half* offp = off_h + (size_t)(b * 49) * 392 + h * 98;
  float2 offr[5];
  float biasr[5];
#pragma unroll
  for (int p = 0; p < 5; ++p) {
    int e = tid + p * 256;
    if (e < nslots) {
      unsigned nu = (unsigned)e / 49u;
      int k2 = e - (int)nu * 49;
      unsigned ku = (unsigned)k2;
      int ky = (int)(ku / 7u), kx = k2 - ky * 7;
      __half2 o2 =
          *(const __half2*)(offp + (size_t)(bn0 + (int)nu) * 392 + k2 * 2);
      offr[p] = __half22float2(o2);
      biasr[p] = rpb[h * 169 + (ky + 3) * 13 + (kx + 3)];
    }
  }

  // ---- P1 stage (pure copies) ----
  {
    short8 zz = {0, 0, 0, 0, 0, 0, 0, 0};
    {
      int r = tid >> 2, c4 = tid & 3;
      short8 pk = zz;
      if (r < 49)
        pk = *(const short8*)(qkv_bf + (size_t)(b * 49 + r) * 384 + 128 +
                              h * 32 + c4 * 8);
      *(short8*)&kbs[r * 40 + c4 * 8] = pk;
    }
    if (tid < 128) {
      int r = tid >> 2, c4 = tid & 3;
      short8 pk = zz;
      if (r < rcnt)
        pk = *(const short8*)(qkv_bf + (size_t)(b * 49 + bn0 + r) * 384 +
                              h * 32 + c4 * 8);
      *(short8*)&qbs[r * 40 + c4 * 8] = pk;
    }
    const short* vbase = qkv_bf + (size_t)(b * 49) * 384 + 256 + h * 32;
#pragma unroll
    for (int it = 0; it < 7; ++it) {
      int i = tid + it * 256;
      if (i < 1568) {
        int n = i >> 5;
        int d = i & 31;
        vbT[d * 72 + n] = vbase[(size_t)n * 384 + d];
      }
    }
    for (int i = tid; i < 480; i += 256) {  // zero vbT cols 49..63, all d
      int d = i / 15;
      int j = i - d * 15;
      vbT[d * 72 + 49 + j] = 0;
    }
    float4 z4 = make_float4(0.f, 0.f, 0.f, 0.f);
    for (int i = tid; i < 338; i += 256) *(float4*)&A2f[i * 4] = z4;
    if (tid < 2) A2f[1352 + tid] = 0.f;
    if (tid < 16) S0h[25 * 52 + tid] = __float2half(0.f);
  }
  __syncthreads();  // B1

  // ---- P2: S0h[n][m] = k_m . q_n via mfma(A=k, B=q); fp16 b64 writes ----
  {
    const int mt = wv;
    short8 af = *(const short8*)&kbs[(mt * 16 + lr) * 40 + lg * 8];
    floatx4 z = {0.f, 0.f, 0.f, 0.f};
#pragma unroll
    for (int nt = 0; nt < 2; ++nt) {
      short8 bf = *(const short8*)&qbs[(nt * 16 + lr) * 40 + lg * 8];
      floatx4 c = __builtin_amdgcn_mfma_f32_16x16x32_bf16(af, bf, z, 0, 0, 0);
      int n = nt * 16 + lr;
      int mbase = mt * 16 + lg * 4;
      if (n < 26 && mbase < 52) {  // both guards required (row pitch 52)
        short4 pk;
        pk.x = (short)__half_as_ushort(__float2half(c[0]));
        pk.y = (short)__half_as_ushort(__float2half(c[1]));
        pk.z = (short)__half_as_ushort(__float2half(c[2]));
        pk.w = (short)__half_as_ushort(__float2half(c[3]));
        *(short4*)&S0h[n * 52 + mbase] = pk;
      }
    }
  }
  __syncthreads();  // B2

  // ---- P3: scores + exp + unnormalized scatter ----
#pragma unroll
  for (int p = 0; p < 5; ++p) {
    int e = tid + p * 256;
    if (e < nslots) {
      unsigned nu = (unsigned)e / 49u;
      int n = (int)nu;
      int k2 = e - n * 49;
      int gn = bn0 + n;
      unsigned gnu = (unsigned)gn;
      int iy = (int)(gnu / 7u), ix = gn - iy * 7;
      unsigned ku = (unsigned)k2;
      int ky = (int)(ku / 7u), kx = k2 - ky * 7;
      float py = fminf(fmaxf((float)(iy + ky - 3) + offr[p].x, 0.f), 6.f);
      float px = fminf(fmaxf((float)(ix + kx - 3) + offr[p].y, 0.f), 6.f);
      float y0f = floorf(py), x0f = floorf(px);
      float wy = py - y0f, wx = px - x0f;
      int base = n * 52 + (int)y0f * 7 + (int)x0f;
      float s00 = __half2float(S0h[base]);
      float s01 = __half2float(S0h[base + 1]);
      float s10 = __half2float(S0h[base + 7]);
      float s11 = __half2float(S0h[base + 8]);
      float w00 = (1.f - wy) * (1.f - wx);
      float w01 = (1.f - wy) * wx;
      float w10 = wy * (1.f - wx);
      float w11 = wy * wx;
      float s = w00 * s00 + w01 * s01 + w10 * s10 + w11 * s11 + biasr[p];
      float pe = __expf(s);
      atomicAdd(&A2f[base], pe * w00);
      atomicAdd(&A2f[base + 1], pe * w01);
      atomicAdd(&A2f[base + 7], pe * w10);
      atomicAdd(&A2f[base + 8], pe * w11);
    }
  }
  __syncthreads();  // B3

  // ---- P4: A2f -> A2b bf16 [32][72]; cols 48+ masked ----
  if (tid < 208) {
    int n = tid >> 3;
    int j8 = tid & 7;
    short8 pk = {0, 0, 0, 0, 0, 0, 0, 0};
    if (j8 < 6) {
      const float* src = &A2f[n * 52 + j8 * 8];
      float4 f0 = *(const float4*)(src);
      float4 f1 = *(const float4*)(src + 4);
      pk[0] = f2bf(f0.x); pk[1] = f2bf(f0.y); pk[2] = f2bf(f0.z); pk[3] = f2bf(f0.w);
      pk[4] = f2bf(f1.x); pk[5] = f2bf(f1.y); pk[6] = f2bf(f1.z); pk[7] = f2bf(f1.w);
    } else if (j8 == 6) {
      pk[0] = f2bf(A2f[n * 52 + 48]);
    }
    *(short8*)&A2b[n * 72 + j8 * 8] = pk;
  }
  __syncthreads();  // B4

  // ---- P5: out + rowsum via MFMA ----
  {
    const int nt = wv & 1;
    const int dt = wv >> 1;
    floatx4 acc = {0.f, 0.f, 0.f, 0.f};
    floatx4 accS = {0.f, 0.f, 0.f, 0.f};
    short8 bones;
#pragma unroll
    for (int u = 0; u < 8; ++u) bones[u] = (lr == 0) ? (short)0x3F80 : (short)0;
#pragma unroll
    for (int ks = 0; ks < 2; ++ks) {
      short8 af = *(const short8*)&A2b[(nt * 16 + lr) * 72 + ks * 32 + lg * 8];
      short8 bf = *(const short8*)&vbT[(dt * 16 + lr) * 72 + ks * 32 + lg * 8];
      acc = __builtin_amdgcn_mfma_f32_16x16x32_bf16(af, bf, acc, 0, 0, 0);
      if (dt == 0)
        accS = __builtin_amdgcn_mfma_f32_16x16x32_bf16(af, bones, accS, 0, 0, 0);
    }
    const int d = dt * 16 + lr;
#pragma unroll
    for (int reg = 0; reg < 4; ++reg) {
      int n = nt * 16 + lg * 4 + reg;
      if (n < rcnt) {
        int grow = b * 49 + bn0 + n;
        attn_out[(size_t)grow * 128 + h * 32 + d] = acc[reg];
        if (dt == 0 && lr == 0) rs_buf[(size_t)grow * 4 + h] = accS[reg];
      }
    }
  }
}

// ---------------------------------------------------------------------------
// Proj GEMM: out = diag(1/rs per head) * attn_out @ w_proj^T + b_proj
// ---------------------------------------------------------------------------
__global__ __launch_bounds__(256) void dwa_proj(
    const float* __restrict__ A, const float* __restrict__ W0,
    const float* __restrict__ bias0, float* __restrict__ out0,
    const float* __restrict__ rs) {
  __shared__ short Abs[64][128];
  __shared__ short Bbs[64][128];
  const int tid = threadIdx.x;
  const int m0 = blockIdx.x * 64;
  const int n0 = blockIdx.y * 64;

#pragma unroll
  for (int p = 0; p < 4; ++p) {
    int c = tid + p * 256;
    int row = c >> 4;
    int slot = c & 15;
    const float* src = A + (size_t)(m0 + row) * 128 + slot * 8;
    float4 f0 = *(const float4*)(src);
    float4 f1 = *(const float4*)(src + 4);
    float irs = 1.0f / rs[(size_t)(m0 + row) * 4 + (slot >> 2)];
    f0.x *= irs; f0.y *= irs; f0.z *= irs; f0.w *= irs;
    f1.x *= irs; f1.y *= irs; f1.z *= irs; f1.w *= irs;
    short8 pk;
    pk[0] = f2bf(f0.x); pk[1] = f2bf(f0.y); pk[2] = f2bf(f0.z); pk[3] = f2bf(f0.w);
    pk[4] = f2bf(f1.x); pk[5] = f2bf(f1.y); pk[6] = f2bf(f1.z); pk[7] = f2bf(f1.w);
    *(short8*)&Abs[row][(slot ^ (row & 7)) * 8] = pk;
  }
#pragma unroll
  for (int p = 0; p < 4; ++p) {
    int c = tid + p * 256;
    int row = c >> 4;
    int slot = c & 15;
    const float* src = W0 + (size_t)(n0 + row) * 128 + slot * 8;
    float4 f0 = *(const float4*)(src);
    float4 f1 = *(const float4*)(src + 4);
    short8 pk;
    pk[0] = f2bf(f0.x); pk[1] = f2bf(f0.y); pk[2] = f2bf(f0.z); pk[3] = f2bf(f0.w);
    pk[4] = f2bf(f1.x); pk[5] = f2bf(f1.y); pk[6] = f2bf(f1.z); pk[7] = f2bf(f1.w);
    *(short8*)&Bbs[row][(slot ^ (row & 7)) * 8] = pk;
  }
  __syncthreads();

  const int lane = tid & 63;
  const int wv = tid >> 6;
  const int wrow = (wv >> 1) * 32;
  const int wcol = (wv & 1) * 32;
  const int lr = lane & 15;
  const int lg = lane >> 4;

  floatx4 acc[2][2];
#pragma unroll
  for (int i = 0; i < 2; ++i)
#pragma unroll
    for (int j = 0; j < 2; ++j) acc[i][j] = {0.f, 0.f, 0.f, 0.f};

#pragma unroll
  for (int ks = 0; ks < 4; ++ks) {
    short8 af[2], bf[2];
#pragma unroll
    for (int i = 0; i < 2; ++i) {
      int r = wrow + i * 16 + lr;
      int slot = (ks * 4 + lg) ^ (r & 7);
      af[i] = *(const short8*)&Abs[r][slot * 8];
    }
#pragma unroll
    for (int j = 0; j < 2; ++j) {
      int r = wcol + j * 16 + lr;
      int slot = (ks * 4 + lg) ^ (r & 7);
      bf[j] = *(const short8*)&Bbs[r][slot * 8];
    }
#pragma unroll
    for (int i = 0; i < 2; ++i)
#pragma unroll
      for (int j = 0; j < 2; ++j)
        acc[i][j] = __builtin_amdgcn_mfma_f32_16x16x32_bf16(af[i], bf[j],
                                                            acc[i][j], 0, 0, 0);
  }

#pragma unroll
  for (int i = 0; i < 2; ++i) {
#pragma unroll
    for (int reg = 0; reg < 4; ++reg) {
      int grow = m0 + wrow + i * 16 + lg * 4 + reg;
#pragma unroll
      for (int j = 0; j < 2; ++j) {
        int gcol = n0 + wcol + j * 16 + lr;
        out0[(size_t)grow * 128 + gcol] = acc[i][j][reg] + bias0[gcol];
      }
    }
  }
}

// ---------------------------------------------------------------------------
extern "C" void kernel_launch(void* const* d_in, const int* in_sizes, int n_in,
                              void* d_out, int out_size, void* d_ws,
                              size_t ws_size, hipStream_t stream) {
  const float* x = (const float*)d_in[0];
  const float* w_qkv = (const float*)d_in[1];
  const float* b_qkv = (const float*)d_in[2];
  const float* w_off = (const float*)d_in[3];
  const float* b_off = (const float*)d_in[4];
  const float* rpb = (const float*)d_in[5];
  const float* w_proj = (const float*)d_in[6];
  const float* b_proj = (const float*)d_in[7];
  float* out = (float*)d_out;

  char* ws = (char*)d_ws;
  short* qkv_bf = (short*)ws;                              // 12544*384*2B
  __half* off_h = (__half*)(ws + (size_t)MROWS * 384 * 2); // 12544*392*2B
  float* attn_out = (float*)(ws + (size_t)MROWS * 384 * 2 +
                             (size_t)MROWS * 392 * 2);     // 12544*128*4B
  float* rs_buf = attn_out + (size_t)MROWS * 128;          // 12544*4

  dwa_gemm0<<<dim3(196, 5), 256, 0, stream>>>(x, w_qkv, w_off, b_qkv, b_off,
                                              qkv_bf, off_h);
  dwa_attn<<<2048, 256, 0, stream>>>(qkv_bf, off_h, rpb, attn_out, rs_buf);
  dwa_proj<<<dim3(196, 2), 256, 0, stream>>>(attn_out, w_proj, b_proj, out,
                                             rs_buf);
}